// Round 1
// baseline (42176.968 us; speedup 1.0000x reference)
//
#include <hip/hip_runtime.h>
#include <cstdint>
#include <cstddef>

// Problem constants
#define B_    16
#define L_    512
#define M_    7
#define BM_   112
#define P_    16
#define S_    8
#define N_    64
#define D_    4096
#define H_    32
#define KV_   8
#define HD_   128
#define DFF_  14336
#define FC_   128
#define PRED_ 96
#define TOK_  7168   // BM_*N_
#define EPS_  1e-5f

// ---------------- instance-norm stats (per b,m over L) ----------------
__global__ __launch_bounds__(256) void stats_kernel(const float* __restrict__ x,
                                                    float* __restrict__ means,
                                                    float* __restrict__ stdev) {
  const int bm = blockIdx.x;
  const int b = bm / M_, m = bm % M_;
  __shared__ float s1[256], s2[256];
  float v1 = 0.f, v2 = 0.f;
  for (int l = threadIdx.x; l < L_; l += 256) {
    float v = x[((size_t)b * L_ + l) * M_ + m];
    v1 += v; v2 += v * v;
  }
  s1[threadIdx.x] = v1; s2[threadIdx.x] = v2;
  __syncthreads();
  for (int s = 128; s > 0; s >>= 1) {
    if (threadIdx.x < s) { s1[threadIdx.x] += s1[threadIdx.x + s]; s2[threadIdx.x] += s2[threadIdx.x + s]; }
    __syncthreads();
  }
  if (threadIdx.x == 0) {
    float mean = s1[0] / (float)L_;
    float var = s2[0] / (float)L_ - mean * mean;
    means[bm] = mean;
    stdev[bm] = sqrtf(var + EPS_);
  }
}

// ------------- normalize + patchify + W_in projection (K=16) -------------
__global__ __launch_bounds__(256) void embed_kernel(const float* __restrict__ x,
                                                    const float* __restrict__ W_in,
                                                    const float* __restrict__ b_in,
                                                    const float* __restrict__ means,
                                                    const float* __restrict__ stdev,
                                                    float* __restrict__ h) {
  const int blk = blockIdx.x;            // bm*N_ + n
  const int bm = blk >> 6, n = blk & 63;
  const int b = bm / M_, m = bm % M_;
  __shared__ float sp[P_];
  if (threadIdx.x < P_) {
    int l = n * S_ + threadIdx.x;
    if (l > L_ - 1) l = L_ - 1;          // replication pad
    sp[threadIdx.x] = (x[((size_t)b * L_ + l) * M_ + m] - means[bm]) / stdev[bm];
  }
  __syncthreads();
  float p[P_];
#pragma unroll
  for (int i = 0; i < P_; i++) p[i] = sp[i];
  for (int d = threadIdx.x; d < D_; d += 256) {
    const float* w = W_in + (size_t)d * P_;
    float acc = b_in[d];
#pragma unroll
    for (int i = 0; i < P_; i++) acc += p[i] * w[i];
    h[(size_t)blk * D_ + d] = acc;
  }
}

// ---------------- RMSNorm over D per token ----------------
__global__ __launch_bounds__(256) void rmsnorm_kernel(const float* __restrict__ in,
                                                      const float* __restrict__ w,
                                                      float* __restrict__ out) {
  const int row = blockIdx.x;
  const float* p = in + (size_t)row * D_;
  float ss = 0.f;
  for (int i = threadIdx.x; i < D_ / 4; i += 256) {
    float4 v = ((const float4*)p)[i];
    ss += v.x * v.x + v.y * v.y + v.z * v.z + v.w * v.w;
  }
  __shared__ float red[256];
  red[threadIdx.x] = ss;
  __syncthreads();
  for (int s = 128; s > 0; s >>= 1) {
    if (threadIdx.x < s) red[threadIdx.x] += red[threadIdx.x + s];
    __syncthreads();
  }
  __shared__ float scale_s;
  if (threadIdx.x == 0) scale_s = rsqrtf(red[0] / (float)D_ + EPS_);
  __syncthreads();
  const float scale = scale_s;
  float* o = out + (size_t)row * D_;
  for (int i = threadIdx.x; i < D_ / 4; i += 256) {
    float4 v = ((const float4*)p)[i];
    float4 wv = ((const float4*)w)[i];
    float4 r;
    r.x = v.x * scale * wv.x; r.y = v.y * scale * wv.y;
    r.z = v.z * scale * wv.z; r.w = v.w * scale * wv.w;
    ((float4*)o)[i] = r;
  }
}

// ---------------- RoPE in place; t is (TOK_, heads, 128) ----------------
__global__ __launch_bounds__(256) void rope_kernel(float* __restrict__ t, int logh, size_t total) {
  size_t idx = (size_t)blockIdx.x * 256 + threadIdx.x;
  if (idx >= total) return;
  const int d = (int)(idx & 63);
  size_t rem = idx >> 6;
  const int heads = 1 << logh;
  const int hh = (int)(rem & (size_t)(heads - 1));
  const size_t tok = rem >> logh;
  const int n = (int)(tok & 63);          // patch position
  // inv_freq = 500000^(-d/64) ; ln(500000)/64 = 0.20503692777194264
  float inv = expf(-(float)d * 0.20503692777194264f);
  float ang = (float)n * inv;
  float s, c;
  sincosf(ang, &s, &c);
  float* base = t + tok * ((size_t)heads * HD_) + (size_t)hh * HD_ + d;
  float x1 = base[0], x2 = base[64];
  base[0]  = x1 * c - x2 * s;
  base[64] = x2 * c + x1 * s;
}

// ---------------- generic fp32 GEMM: C(MxN) = A(MxK) * B(NxK)^T ----------------
// modes: 0 plain ; 1 C = res + acc ; 2 C = silu(C_old) * acc ; 3 atomicAdd(C, acc)
#define GTK 16
__global__ __launch_bounds__(256) void gemm_bt(const float* __restrict__ A,
                                               const float* __restrict__ B,
                                               float* __restrict__ C,
                                               const float* __restrict__ res,
                                               int M, int N, int K,
                                               int lda, int ldb, int ldc,
                                               int KC, int mode) {
  __shared__ float As[GTK][68];
  __shared__ float Bs[GTK][68];
  const int tid = threadIdx.x;
  const int m0 = blockIdx.y << 6;
  const int n0 = blockIdx.x << 6;
  const int k0 = blockIdx.z * KC;
  const int tr = ((tid >> 4) & 15) << 2;   // row offset in tile
  const int tc = (tid & 15) << 2;          // col offset in tile
  const int lr = tid >> 2;                 // load row 0..63
  const int lk = (tid & 3) << 2;           // load k offset 0/4/8/12
  int ar = m0 + lr; if (ar >= M) ar = M - 1;
  const float* aptr = A + (size_t)ar * lda + (size_t)k0 + lk;
  const float* bptr = B + (size_t)(n0 + lr) * ldb + (size_t)k0 + lk;
  float acc[4][4] = {};
  const int iters = KC / GTK;
  for (int it = 0; it < iters; it++) {
    float4 av = *(const float4*)aptr;
    float4 bv = *(const float4*)bptr;
    aptr += GTK; bptr += GTK;
    __syncthreads();
    As[lk + 0][lr] = av.x; As[lk + 1][lr] = av.y; As[lk + 2][lr] = av.z; As[lk + 3][lr] = av.w;
    Bs[lk + 0][lr] = bv.x; Bs[lk + 1][lr] = bv.y; Bs[lk + 2][lr] = bv.z; Bs[lk + 3][lr] = bv.w;
    __syncthreads();
#pragma unroll
    for (int k = 0; k < GTK; k++) {
      float4 a = *(const float4*)&As[k][tr];
      float4 b = *(const float4*)&Bs[k][tc];
      acc[0][0] += a.x * b.x; acc[0][1] += a.x * b.y; acc[0][2] += a.x * b.z; acc[0][3] += a.x * b.w;
      acc[1][0] += a.y * b.x; acc[1][1] += a.y * b.y; acc[1][2] += a.y * b.z; acc[1][3] += a.y * b.w;
      acc[2][0] += a.z * b.x; acc[2][1] += a.z * b.y; acc[2][2] += a.z * b.z; acc[2][3] += a.z * b.w;
      acc[3][0] += a.w * b.x; acc[3][1] += a.w * b.y; acc[3][2] += a.w * b.z; acc[3][3] += a.w * b.w;
    }
  }
#pragma unroll
  for (int i = 0; i < 4; i++) {
    const int r = m0 + tr + i;
    if (r < M) {
      const size_t off = (size_t)r * ldc + n0 + tc;
#pragma unroll
      for (int j = 0; j < 4; j++) {
        const float val = acc[i][j];
        if (mode == 0) {
          C[off + j] = val;
        } else if (mode == 1) {
          C[off + j] = res[off + j] + val;
        } else if (mode == 2) {
          const float g = C[off + j];
          C[off + j] = (g / (1.f + expf(-g))) * val;
        } else {
          atomicAdd(&C[off + j], val);
        }
      }
    }
  }
}

// ---------------- attention: one block per (bm, head) ----------------
// q (TOK_, H_*HD_) rope'd; k,v (TOK_, KV_*HD_); o written over q slice.
__global__ __launch_bounds__(256) void attn_kernel(float* __restrict__ q,
                                                   const float* __restrict__ k,
                                                   const float* __restrict__ v) {
  __shared__ float r1[64 * 128];   // q (swizzled) -> then scores sc[64][65]
  __shared__ float r2[64 * 128];   // k (swizzled) -> then v (swizzled)
  const int tid = threadIdx.x;
  const int bm = blockIdx.x >> 5, hh = blockIdx.x & 31, kvh = hh >> 2;
  const size_t qbase = (size_t)bm * (64 * 4096) + (size_t)hh * 128;
  const size_t kvbase = (size_t)bm * (64 * 1024) + (size_t)kvh * 128;
  // stage q,k (XOR-swizzled float4 columns to dodge bank conflicts)
  for (int i = tid; i < 64 * 32; i += 256) {
    const int r = i >> 5, d4 = i & 31;
    const int cg = d4 ^ ((r >> 2) & 15);
    float4 qv = *(const float4*)(q + qbase + (size_t)r * 4096 + (size_t)d4 * 4);
    float4 kv = *(const float4*)(k + kvbase + (size_t)r * 1024 + (size_t)d4 * 4);
    *(float4*)(r1 + r * 128 + cg * 4) = qv;
    *(float4*)(r2 + r * 128 + cg * 4) = kv;
  }
  __syncthreads();
  const int tq = ((tid >> 4) & 15) << 2;
  const int tk = (tid & 15) << 2;
  float acc[4][4] = {};
  for (int d4 = 0; d4 < 32; d4++) {
    float4 a[4], bb[4];
#pragma unroll
    for (int i = 0; i < 4; i++) {
      const int row = tq + i;
      a[i] = *(const float4*)(r1 + row * 128 + ((d4 ^ ((row >> 2) & 15)) << 2));
    }
#pragma unroll
    for (int j = 0; j < 4; j++) {
      const int row = tk + j;
      bb[j] = *(const float4*)(r2 + row * 128 + ((d4 ^ ((row >> 2) & 15)) << 2));
    }
#pragma unroll
    for (int i = 0; i < 4; i++)
#pragma unroll
      for (int j = 0; j < 4; j++)
        acc[i][j] += a[i].x * bb[j].x + a[i].y * bb[j].y + a[i].z * bb[j].z + a[i].w * bb[j].w;
  }
  __syncthreads();
  // scores -> r1 as sc[64][65] (causal mask + scale); v -> r2
  const float scale = 0.08838834764831845f;   // 1/sqrt(128)
#pragma unroll
  for (int i = 0; i < 4; i++)
#pragma unroll
    for (int j = 0; j < 4; j++) {
      const int qi = tq + i, ki = tk + j;
      r1[qi * 65 + ki] = (ki > qi) ? -1e9f : acc[i][j] * scale;
    }
  for (int i = tid; i < 64 * 32; i += 256) {
    const int r = i >> 5, d4 = i & 31;
    const int cg = d4 ^ ((r >> 2) & 15);
    float4 vv = *(const float4*)(v + kvbase + (size_t)r * 1024 + (size_t)d4 * 4);
    *(float4*)(r2 + r * 128 + cg * 4) = vv;
  }
  __syncthreads();
  // softmax per row (threads 0..63)
  if (tid < 64) {
    float mx = -1e30f;
    for (int j = 0; j < 64; j++) mx = fmaxf(mx, r1[tid * 65 + j]);
    float sum = 0.f;
    for (int j = 0; j < 64; j++) {
      float e = expf(r1[tid * 65 + j] - mx);
      r1[tid * 65 + j] = e; sum += e;
    }
    float inv = 1.f / sum;
    for (int j = 0; j < 64; j++) r1[tid * 65 + j] *= inv;
  }
  __syncthreads();
  // PV: o[qi][d] = sum_ki sc[qi][ki] * v[ki][d]; write over q slice
  const int qg = ((tid >> 4) & 15) << 2;
  const int dgl = tid & 15;
#pragma unroll
  for (int half = 0; half < 2; half++) {
    const int d4 = dgl + 16 * half;
    float oo[4][4] = {};
    for (int ki = 0; ki < 64; ki++) {
      const float4 vv = *(const float4*)(r2 + ki * 128 + ((d4 ^ ((ki >> 2) & 15)) << 2));
      const float s0 = r1[(qg + 0) * 65 + ki];
      const float s1 = r1[(qg + 1) * 65 + ki];
      const float s2 = r1[(qg + 2) * 65 + ki];
      const float s3 = r1[(qg + 3) * 65 + ki];
      oo[0][0] += s0 * vv.x; oo[0][1] += s0 * vv.y; oo[0][2] += s0 * vv.z; oo[0][3] += s0 * vv.w;
      oo[1][0] += s1 * vv.x; oo[1][1] += s1 * vv.y; oo[1][2] += s1 * vv.z; oo[1][3] += s1 * vv.w;
      oo[2][0] += s2 * vv.x; oo[2][1] += s2 * vv.y; oo[2][2] += s2 * vv.z; oo[2][3] += s2 * vv.w;
      oo[3][0] += s3 * vv.x; oo[3][1] += s3 * vv.y; oo[3][2] += s3 * vv.z; oo[3][3] += s3 * vv.w;
    }
#pragma unroll
    for (int i = 0; i < 4; i++) {
      float4 w4 = make_float4(oo[i][0], oo[i][1], oo[i][2], oo[i][3]);
      *(float4*)(q + qbase + (size_t)(qg + i) * 4096 + (size_t)d4 * 4) = w4;
    }
  }
}

// ---------------- head: bias + LeakyReLU + (96x128) matvec + denorm ----------------
__global__ __launch_bounds__(128) void head_kernel(const float* __restrict__ z,
                                                   const float* __restrict__ b_fc,
                                                   const float* __restrict__ W_out,
                                                   const float* __restrict__ b_out,
                                                   const float* __restrict__ means,
                                                   const float* __restrict__ stdev,
                                                   float* __restrict__ out) {
  const int i = blockIdx.x;             // bm
  const int b = i / M_, m = i % M_;
  __shared__ float zz[FC_];
  const int tid = threadIdx.x;
  float vv = z[(size_t)i * FC_ + tid] + b_fc[tid];
  zz[tid] = vv > 0.f ? vv : 0.01f * vv;
  __syncthreads();
  if (tid < PRED_) {
    float acc = b_out[tid];
    const float* w = W_out + (size_t)tid * FC_;
    for (int f = 0; f < FC_; f++) acc += zz[f] * w[f];
    out[((size_t)b * PRED_ + tid) * M_ + m] = acc * stdev[i] + means[i];
  }
}

// ---------------- launch ----------------
extern "C" void kernel_launch(void* const* d_in, const int* in_sizes, int n_in,
                              void* d_out, int out_size, void* d_ws, size_t ws_size,
                              hipStream_t stream) {
  (void)in_sizes; (void)n_in; (void)out_size; (void)ws_size;
  const float* x      = (const float*)d_in[0];
  const float* W_in   = (const float*)d_in[1];
  const float* b_in   = (const float*)d_in[2];
  const float* attn_w = (const float*)d_in[3];
  const float* Wq     = (const float*)d_in[4];
  const float* Wk     = (const float*)d_in[5];
  const float* Wv     = (const float*)d_in[6];
  const float* Wo     = (const float*)d_in[7];
  const float* mlp_w  = (const float*)d_in[8];
  const float* Wg     = (const float*)d_in[9];
  const float* Wu     = (const float*)d_in[10];
  const float* Wd     = (const float*)d_in[11];
  const float* fin_w  = (const float*)d_in[12];
  const float* W_fc   = (const float*)d_in[13];
  const float* b_fc   = (const float*)d_in[14];
  const float* W_out  = (const float*)d_in[15];
  const float* b_out  = (const float*)d_in[16];
  float* out = (float*)d_out;

  // workspace layout (floats): total ~102.8M floats (~411 MB)
  float* ws = (float*)d_ws;
  float* h   = ws;                                  // 7168*4096
  float* hn  = h  + (size_t)TOK_ * D_;              // 7168*4096
  float* qb  = hn + (size_t)TOK_ * D_;              // 7168*4096 (later: o, later: mlp chunk)
  float* kb  = qb + (size_t)TOK_ * D_;              // 7168*1024
  float* vb  = kb + (size_t)TOK_ * (KV_ * HD_);     // 7168*1024
  float* stats = vb + (size_t)TOK_ * (KV_ * HD_);
  float* means = stats;
  float* stdev = stats + BM_;
  float* zb    = stats + 256;                       // 112*128
  float* chunk = qb;                                // reuse q region for MLP chunk

  hipMemsetAsync(zb, 0, (size_t)BM_ * FC_ * sizeof(float), stream);

  stats_kernel<<<BM_, 256, 0, stream>>>(x, means, stdev);
  embed_kernel<<<TOK_, 256, 0, stream>>>(x, W_in, b_in, means, stdev, h);
  rmsnorm_kernel<<<TOK_, 256, 0, stream>>>(h, attn_w, hn);

  // QKV projections
  {
    dim3 gq(D_ / 64, TOK_ / 64, 1);
    gemm_bt<<<gq, 256, 0, stream>>>(hn, Wq, qb, nullptr, TOK_, D_, D_, D_, D_, D_, D_, 0);
    dim3 gkv((KV_ * HD_) / 64, TOK_ / 64, 1);
    gemm_bt<<<gkv, 256, 0, stream>>>(hn, Wk, kb, nullptr, TOK_, KV_ * HD_, D_, D_, D_, KV_ * HD_, D_, 0);
    gemm_bt<<<gkv, 256, 0, stream>>>(hn, Wv, vb, nullptr, TOK_, KV_ * HD_, D_, D_, D_, KV_ * HD_, D_, 0);
  }
  // RoPE
  {
    size_t tq = (size_t)TOK_ * H_ * 64;
    rope_kernel<<<(unsigned)((tq + 255) / 256), 256, 0, stream>>>(qb, 5, tq);
    size_t tk = (size_t)TOK_ * KV_ * 64;
    rope_kernel<<<(unsigned)((tk + 255) / 256), 256, 0, stream>>>(kb, 3, tk);
  }
  attn_kernel<<<BM_ * H_, 256, 0, stream>>>(qb, kb, vb);
  // o projection + residual into h
  {
    dim3 gq(D_ / 64, TOK_ / 64, 1);
    gemm_bt<<<gq, 256, 0, stream>>>(qb, Wo, h, h, TOK_, D_, D_, D_, D_, D_, D_, 1);
  }
  rmsnorm_kernel<<<TOK_, 256, 0, stream>>>(h, mlp_w, hn);
  // SwiGLU MLP in 4 chunks of DFF
  {
    const int CH = DFF_ / 4;   // 3584
    dim3 gg(CH / 64, TOK_ / 64, 1);
    dim3 gd(D_ / 64, TOK_ / 64, 1);
    for (int c = 0; c < 4; c++) {
      gemm_bt<<<gg, 256, 0, stream>>>(hn, Wg + (size_t)c * CH * D_, chunk, nullptr,
                                      TOK_, CH, D_, D_, D_, CH, D_, 0);
      gemm_bt<<<gg, 256, 0, stream>>>(hn, Wu + (size_t)c * CH * D_, chunk, nullptr,
                                      TOK_, CH, D_, D_, D_, CH, D_, 2);
      gemm_bt<<<gd, 256, 0, stream>>>(chunk, Wd + (size_t)c * CH, h, h,
                                      TOK_, D_, CH, CH, DFF_, D_, CH, 1);
    }
  }
  rmsnorm_kernel<<<TOK_, 256, 0, stream>>>(h, fin_w, hn);
  // fc: z(112x128) = hn.view(112, 262144) @ W_fc^T  (k-split atomic)
  {
    dim3 gz(FC_ / 64, (BM_ + 63) / 64, 64);
    gemm_bt<<<gz, 256, 0, stream>>>(hn, W_fc, zb, nullptr,
                                    BM_, FC_, N_ * D_, N_ * D_, N_ * D_, FC_, 4096, 3);
  }
  head_kernel<<<BM_, 128, 0, stream>>>(zb, b_fc, W_out, b_out, means, stdev, out);
}